// Round 1
// baseline (558.741 us; speedup 1.0000x reference)
//
#include <hip/hip_runtime.h>
#include <hip/hip_bf16.h>

#define HID 256
#define NN 8192
#define NBATCH 2
#define NE 262144

typedef float f32x4 __attribute__((ext_vector_type(4)));
typedef __bf16 bf16x8 __attribute__((ext_vector_type(8)));
typedef __bf16 bf16x4 __attribute__((ext_vector_type(4)));

// ---------------- weight conversion: f32 -> bf16, [Wq][Wk][Wv][We] ----------------
__global__ void conv_weights(const float* __restrict__ wq, const float* __restrict__ wk,
                             const float* __restrict__ wv, const float* __restrict__ we,
                             __bf16* __restrict__ o) {
    int i = blockIdx.x * 256 + threadIdx.x;          // 0 .. 4*65536-1
    const float* srcs[4] = {wq, wk, wv, we};
    int m = i >> 16;
    int j = i & 65535;
    o[i] = (__bf16)srcs[m][j];
}

// ---------------- QKV projection: Q/K/V = x @ W^T + b (M=16384,N=256,K=256) -------
__global__ void qkv_gemm(const float* __restrict__ x,
                         const __bf16* __restrict__ wbf,
                         const float* __restrict__ bq, const float* __restrict__ bk,
                         const float* __restrict__ bv,
                         float* __restrict__ qkv) {
    __shared__ __bf16 xt[64 * 256];
    char* lb = (char*)xt;
    int tid = threadIdx.x;
    int blk = blockIdx.x;

    // stage 64x256 f32 tile -> bf16 LDS, XOR-swizzled (G4: break 512B row stride)
    const float4* xs = (const float4*)(x + (size_t)blk * 64 * 256);
    #pragma unroll
    for (int kq = 0; kq < 16; ++kq) {
        int f = tid + kq * 256;         // float4 index within tile
        int row = f >> 6, c4 = f & 63;
        float4 v = xs[f];
        bf16x4 h;
        h[0] = (__bf16)v.x; h[1] = (__bf16)v.y; h[2] = (__bf16)v.z; h[3] = (__bf16)v.w;
        int off = (row * 512 + c4 * 8) ^ ((row & 7) << 4);
        *(bf16x4*)(lb + off) = h;
    }
    __syncthreads();

    int w = tid >> 6, lane = tid & 63;
    int l15 = lane & 15, l4 = lane >> 4;
    const float* biases[3] = {bq, bk, bv};

    for (int m = 0; m < 3; ++m) {
        const __bf16* W = wbf + (size_t)m * 65536;   // row-major [n][k] == B^T
        f32x4 acc[4][4] = {};
        for (int ks = 0; ks < 8; ++ks) {
            bf16x8 a[4], b[4];
            #pragma unroll
            for (int tm = 0; tm < 4; ++tm) {
                int row = tm * 16 + l15;
                int off = (row * 512 + ks * 64 + l4 * 16) ^ ((row & 7) << 4);
                a[tm] = *(const bf16x8*)(lb + off);
            }
            #pragma unroll
            for (int tn = 0; tn < 4; ++tn) {
                int col = w * 64 + tn * 16 + l15;
                b[tn] = *(const bf16x8*)(W + (size_t)col * 256 + ks * 32 + l4 * 8);
            }
            #pragma unroll
            for (int tm = 0; tm < 4; ++tm)
                #pragma unroll
                for (int tn = 0; tn < 4; ++tn)
                    acc[tm][tn] = __builtin_amdgcn_mfma_f32_16x16x32_bf16(a[tm], b[tn], acc[tm][tn], 0, 0, 0);
        }
        float* out = qkv + (size_t)m * 16384 * 256;
        #pragma unroll
        for (int tn = 0; tn < 4; ++tn) {
            int col = w * 64 + tn * 16 + l15;
            float bias = biases[m][col];
            #pragma unroll
            for (int tm = 0; tm < 4; ++tm)
                #pragma unroll
                for (int r = 0; r < 4; ++r) {
                    int grow = blk * 64 + tm * 16 + l4 * 4 + r;
                    out[(size_t)grow * 256 + col] = acc[tm][tn][r] + bias;
                }
        }
    }
}

// ---------------- fused edge kernel: Ke/Ve MFMA + logits + softmax + scatter ------
__global__ void edge_attn(const float* __restrict__ ev,
                          const int* __restrict__ eidx,
                          const __bf16* __restrict__ wbf,
                          const float* __restrict__ bkb, const float* __restrict__ beb,
                          const float* __restrict__ qkv,
                          float* __restrict__ out) {
    __shared__ __bf16 evt[64 * 256];
    __shared__ int sb[64], ss[64], st[64];
    __shared__ float smx[64 * 8];
    char* lb = (char*)evt;
    int tid = threadIdx.x;
    int e0 = blockIdx.x * 64;

    const float4* xs = (const float4*)(ev + (size_t)e0 * 256);
    #pragma unroll
    for (int kq = 0; kq < 16; ++kq) {
        int f = tid + kq * 256;
        int row = f >> 6, c4 = f & 63;
        float4 v = xs[f];
        bf16x4 h;
        h[0] = (__bf16)v.x; h[1] = (__bf16)v.y; h[2] = (__bf16)v.z; h[3] = (__bf16)v.w;
        int off = (row * 512 + c4 * 8) ^ ((row & 7) << 4);
        *(bf16x4*)(lb + off) = h;
    }
    if (tid < 64) {
        sb[tid] = eidx[e0 + tid];
        ss[tid] = eidx[NE + e0 + tid];
        st[tid] = eidx[2 * NE + e0 + tid];
    }
    __syncthreads();

    int w = tid >> 6, lane = tid & 63;
    int l15 = lane & 15, l4 = lane >> 4;
    int cw = w * 64;
    const float* Q = qkv;
    const float* K = qkv + (size_t)16384 * 256;
    const float* V = qkv + (size_t)2 * 16384 * 256;

    // ---- pass 1: Ke = ev @ Wk^T, then logits -> LDS ----
    {
        const __bf16* WK = wbf + 65536;
        f32x4 acc[4][4] = {};
        for (int ks = 0; ks < 8; ++ks) {
            bf16x8 a[4], b[4];
            #pragma unroll
            for (int tm = 0; tm < 4; ++tm) {
                int row = tm * 16 + l15;
                int off = (row * 512 + ks * 64 + l4 * 16) ^ ((row & 7) << 4);
                a[tm] = *(const bf16x8*)(lb + off);
            }
            #pragma unroll
            for (int tn = 0; tn < 4; ++tn) {
                int col = cw + tn * 16 + l15;
                b[tn] = *(const bf16x8*)(WK + (size_t)col * 256 + ks * 32 + l4 * 8);
            }
            #pragma unroll
            for (int tm = 0; tm < 4; ++tm)
                #pragma unroll
                for (int tn = 0; tn < 4; ++tn)
                    acc[tm][tn] = __builtin_amdgcn_mfma_f32_16x16x32_bf16(a[tm], b[tn], acc[tm][tn], 0, 0, 0);
        }
        float bkv[4];
        #pragma unroll
        for (int tn = 0; tn < 4; ++tn) bkv[tn] = bkb[cw + tn * 16 + l15];

        #pragma unroll
        for (int tm = 0; tm < 4; ++tm) {
            #pragma unroll
            for (int r = 0; r < 4; ++r) {
                int el = tm * 16 + l4 * 4 + r;
                int b_ = sb[el], s_ = ss[el], t_ = st[el];
                size_t qbase = ((size_t)b_ * NN + s_) * 256;
                size_t kbase = ((size_t)b_ * NN + t_) * 256;
                #pragma unroll
                for (int hl = 0; hl < 2; ++hl) {
                    float val = 0.f;
                    #pragma unroll
                    for (int j = 0; j < 2; ++j) {
                        int tn = hl * 2 + j;
                        int col = cw + tn * 16 + l15;
                        float ke = acc[tm][tn][r] + bkv[tn];
                        val += Q[qbase + col] * (K[kbase + col] + ke);
                    }
                    val += __shfl_xor(val, 1);
                    val += __shfl_xor(val, 2);
                    val += __shfl_xor(val, 4);
                    val += __shfl_xor(val, 8);
                    if (l15 == 0) smx[el * 8 + w * 2 + hl] = val * 0.17677669529663687f;
                }
            }
        }
    }
    __syncthreads();

    // ---- softmax over the 8 heads of each edge ----
    if (tid < 64) {
        float l[8], mx = -1e30f;
        #pragma unroll
        for (int h = 0; h < 8; ++h) { l[h] = smx[tid * 8 + h]; mx = fmaxf(mx, l[h]); }
        float sum = 0.f;
        #pragma unroll
        for (int h = 0; h < 8; ++h) { l[h] = __expf(l[h] - mx); sum += l[h]; }
        float inv = 1.f / sum;
        #pragma unroll
        for (int h = 0; h < 8; ++h) smx[tid * 8 + h] = l[h] * inv;
    }
    __syncthreads();

    // ---- pass 2: Ve = ev @ We^T, out_edges scatter ----
    {
        const __bf16* WE = wbf + 3 * 65536;
        f32x4 acc[4][4] = {};
        for (int ks = 0; ks < 8; ++ks) {
            bf16x8 a[4], b[4];
            #pragma unroll
            for (int tm = 0; tm < 4; ++tm) {
                int row = tm * 16 + l15;
                int off = (row * 512 + ks * 64 + l4 * 16) ^ ((row & 7) << 4);
                a[tm] = *(const bf16x8*)(lb + off);
            }
            #pragma unroll
            for (int tn = 0; tn < 4; ++tn) {
                int col = cw + tn * 16 + l15;
                b[tn] = *(const bf16x8*)(WE + (size_t)col * 256 + ks * 32 + l4 * 8);
            }
            #pragma unroll
            for (int tm = 0; tm < 4; ++tm)
                #pragma unroll
                for (int tn = 0; tn < 4; ++tn)
                    acc[tm][tn] = __builtin_amdgcn_mfma_f32_16x16x32_bf16(a[tm], b[tn], acc[tm][tn], 0, 0, 0);
        }
        float bev[4];
        #pragma unroll
        for (int tn = 0; tn < 4; ++tn) bev[tn] = beb[cw + tn * 16 + l15];

        #pragma unroll
        for (int tm = 0; tm < 4; ++tm) {
            #pragma unroll
            for (int r = 0; r < 4; ++r) {
                int el = tm * 16 + l4 * 4 + r;
                int b_ = sb[el], s_ = ss[el], t_ = st[el];
                size_t vbase = ((size_t)b_ * NN + t_) * 256;
                size_t obase = ((size_t)b_ * NN + s_) * 256;
                #pragma unroll
                for (int tn = 0; tn < 4; ++tn) {
                    int col = cw + tn * 16 + l15;
                    float a_ = smx[el * 8 + w * 2 + (tn >> 1)];
                    float vv = V[vbase + col] + acc[tm][tn][r] + bev[tn];
                    unsafeAtomicAdd(&out[obase + col], a_ * vv);
                }
            }
        }
    }
}

extern "C" void kernel_launch(void* const* d_in, const int* in_sizes, int n_in,
                              void* d_out, int out_size, void* d_ws, size_t ws_size,
                              hipStream_t stream) {
    const float* node_states = (const float*)d_in[0];
    const int*   eidx        = (const int*)d_in[1];
    const float* ev          = (const float*)d_in[2];
    const float* Wq          = (const float*)d_in[3];
    const float* bq          = (const float*)d_in[4];
    const float* Wk          = (const float*)d_in[5];
    const float* bk          = (const float*)d_in[6];
    const float* Wv          = (const float*)d_in[7];
    const float* bv          = (const float*)d_in[8];
    const float* We          = (const float*)d_in[9];
    const float* be          = (const float*)d_in[10];
    float* out = (float*)d_out;

    float*  qkv = (float*)d_ws;                                  // 3 * 16384*256 f32
    __bf16* wbf = (__bf16*)((char*)d_ws + 3ll * 16384 * 256 * 4); // 4 * 65536 bf16

    hipMemsetAsync(d_out, 0, (size_t)out_size * sizeof(float), stream);
    conv_weights<<<1024, 256, 0, stream>>>(Wq, Wk, Wv, We, wbf);
    qkv_gemm<<<256, 256, 0, stream>>>(node_states, wbf, bq, bk, bv, qkv);
    edge_attn<<<4096, 256, 0, stream>>>(ev, eidx, wbf, bk, be, qkv, out);
}